// Round 6
// baseline (498.536 us; speedup 1.0000x reference)
//
#include <hip/hip_runtime.h>

typedef __bf16 bf16;
typedef __attribute__((ext_vector_type(8))) __bf16 bf16x8;
typedef __attribute__((ext_vector_type(4))) __bf16 bf16x4;
typedef __attribute__((ext_vector_type(4))) float f32x4;

#define B_  32
#define S_  2048
#define DC  1024
#define DQ  1024
#define H_  512
#define NCH 16             // s-chunks for expected_ctx (compacted: 16 x 128 covers 2048)
#define NRB 8              // row-blocks per batch in k_gemm (8 x 256 = 2048 worst case)

// async global->LDS, 16B per lane
#define GLD16(g, l) __builtin_amdgcn_global_load_lds( \
    (__attribute__((address_space(1))) void*)(g),     \
    (__attribute__((address_space(3))) void*)(l), 16, 0, 0)

// ---------- Prep ----------
// blocks 0..255   : Wc -> bf16 transpose tiles  WcT2 [kb(32)][h(512)][kk(32)]
// blocks 256..511 : qb[b][h] = query[b] . Wq[:,h] + b1[h]
// blocks 512..543 : per-batch compaction of mask==1 row indices (global row ids)
__global__ __launch_bounds__(256) void k_prep(const float* __restrict__ W1,
                                              const float* __restrict__ query,
                                              const float* __restrict__ b1,
                                              const int*   __restrict__ mask,
                                              bf16* __restrict__ WcT2,
                                              float* __restrict__ qb,
                                              int* __restrict__ glist,
                                              int* __restrict__ cnts) {
    const int bid = blockIdx.x, tid = threadIdx.x;
    if (bid < 256) {
        // W1[:1024] (k-major) -> WcT2 [kb][h][kk] bf16
        __shared__ bf16 t[32 * 68];            // [kk][h-in-tile], pad 4
        const int kb = bid >> 3;               // 0..31
        const int cb = bid & 7;                // 0..7, 64-col tile
        #pragma unroll
        for (int i = 0; i < 2; ++i) {
            int idx = i * 256 + tid;           // 0..511
            int k  = idx >> 4;                 // 0..31
            int h4 = (idx & 15) * 4;           // 0..60
            const float4 v = *(const float4*)(W1 + ((size_t)(kb * 32 + k)) * H_ + cb * 64 + h4);
            bf16x4 pk = { (bf16)v.x, (bf16)v.y, (bf16)v.z, (bf16)v.w };
            *(bf16x4*)(&t[k * 68 + h4]) = pk;
        }
        __syncthreads();
        const int col = tid >> 2;              // 0..63
        const int kk0 = (tid & 3) * 8;         // 0,8,16,24
        bf16x8 o;
        #pragma unroll
        for (int j = 0; j < 8; ++j) o[j] = t[(kk0 + j) * 68 + col];
        *(bf16x8*)(WcT2 + (size_t)kb * 16384 + (size_t)(cb * 64 + col) * 32 + kk0) = o;
    } else if (bid < 512) {
        // qb GEMV
        const int r = bid - 256;
        const int hblk = r & 7;                // 0..7
        const int b    = r >> 3;               // 0..31
        __shared__ float q[DQ];
        __shared__ float red[256];
        #pragma unroll
        for (int i = 0; i < 4; ++i)
            q[tid + i * 256] = query[(size_t)b * DQ + tid + i * 256];
        __syncthreads();
        const int h  = hblk * 64 + (tid & 63);
        const int kc = tid >> 6;               // 0..3
        const float* w = W1 + (size_t)DC * H_ + (size_t)(kc * 256) * H_ + h;
        const float* qv = q + kc * 256;
        float acc = 0.0f;
        #pragma unroll 8
        for (int k = 0; k < 256; ++k)
            acc = fmaf(qv[k], w[(size_t)k * H_], acc);
        red[tid] = acc;
        __syncthreads();
        if (tid < 64)
            qb[(size_t)b * H_ + hblk * 64 + tid] =
                red[tid] + red[tid + 64] + red[tid + 128] + red[tid + 192] + b1[hblk * 64 + tid];
    } else {
        // compaction: list of global row ids (b*2048+s) where mask==1, padded with b*2048
        const int b = bid - 512;
        __shared__ int sc[256];
        int c = 0;
        #pragma unroll
        for (int i = 0; i < 8; ++i)
            if (mask[(size_t)b * S_ + tid * 8 + i] != 0) ++c;
        sc[tid] = c;
        __syncthreads();
        for (int o = 1; o < 256; o <<= 1) {
            int v = sc[tid];
            int u = (tid >= o) ? sc[tid - o] : 0;
            __syncthreads();
            sc[tid] = v + u;
            __syncthreads();
        }
        const int total = sc[255];
        int w = sc[tid] - c;                   // exclusive offset
        for (int i = 0; i < 8; ++i) {
            int s = tid * 8 + i;
            if (mask[(size_t)b * S_ + s] != 0)
                glist[(size_t)b * S_ + (w++)] = b * S_ + s;
        }
        for (int pos = total + tid; pos < S_; pos += 256)
            glist[(size_t)b * S_ + pos] = b * S_;
        if (tid == 0) cnts[b] = total;
    }
}

// ---------- Kernel G: partial score over one H-half, unmasked rows only ----------
// Round-0 loop skeleton with HALF the k-steps: BK=64 (two 32-k sub-tiles per
// step), M=256 rows, BN=256 cols (h2 twins). 16 barrier quanta instead of 32 —
// rounds 4/5 showed per-step time is a latency constant, so fewer fatter steps.
// LDS 128 KB -> 1 block/CU (round 5 showed residency is not the lever).
// 512 thr = 8 waves (4m x 2n), wave tile 64x128, acc[4][8].
__global__ __launch_bounds__(512, 2) void k_gemm(const float* __restrict__ ctx,
                                                 const bf16*  __restrict__ WcT2,
                                                 const float* __restrict__ qb,
                                                 const float* __restrict__ W2,
                                                 const int*   __restrict__ glist,
                                                 const int*   __restrict__ cnts,
                                                 float* __restrict__ scorep) {
    __shared__ char smem_raw[131072];
    bf16* As = (bf16*)smem_raw;                // [2 buf][2 kseg][256][32]  64 KB
    bf16* Bs = (bf16*)(smem_raw + 65536);      // [2 buf][2 kseg][256][32]  64 KB
    float* red = (float*)smem_raw;             // epilogue reuse of As region

    const int tid = threadIdx.x;
    const int h2  = blockIdx.x & 1;
    const int blk = (blockIdx.x >> 1) & (NRB - 1);
    const int b   = blockIdx.x >> 4;
    const int cnt = cnts[b];
    if (blk * 256 >= cnt) return;

    const int lane = tid & 63;
    const int wave = tid >> 6;
    const int wm   = wave & 3;                 // 4 m-waves x 64 rows
    const int wn   = wave >> 2;                // 2 n-waves x 128 cols
    const int l16  = lane & 15;
    const int quad = lane >> 4;

    f32x4 acc[4][8] = {};

    // A staging: thread -> (row = tid>>1, khalf = tid&1), 32 f32 per step
    const int arow  = tid >> 1;                // 0..255
    const int khalf = tid & 1;
    const int grow = glist[(size_t)b * S_ + blk * 256 + arow];
    const float* actx = ctx + (size_t)grow * DC + khalf * 32;
    const int aoff = khalf * 8192 + arow * 32; // bf16 idx within A buffer

    const bf16* bsrc = WcT2 + (size_t)h2 * 8192 + tid * 8;
    const int boff = tid * 8;
    const int fA = (wm * 64 + l16) * 32 + quad * 8;
    const int fB = (wn * 128 + l16) * 32 + quad * 8;

    // ---- prologue: stage k-step 0 into buffer 0 ----
    {
        #pragma unroll
        for (int ks = 0; ks < 2; ++ks)
            #pragma unroll
            for (int i = 0; i < 2; ++i)
                GLD16(bsrc + (size_t)ks * 16384 + i * 4096,
                      Bs + ks * 8192 + boff + i * 4096);
        float4 v[8];
        #pragma unroll
        for (int i = 0; i < 8; ++i) v[i] = *(const float4*)(actx + i * 4);
        #pragma unroll
        for (int j = 0; j < 4; ++j) {
            bf16x8 a8 = { (bf16)v[2*j].x, (bf16)v[2*j].y, (bf16)v[2*j].z, (bf16)v[2*j].w,
                          (bf16)v[2*j+1].x, (bf16)v[2*j+1].y, (bf16)v[2*j+1].z, (bf16)v[2*j+1].w };
            *(bf16x8*)(As + aoff + j * 8) = a8;
        }
    }
    __syncthreads();

    for (int kb = 0; kb < DC / 64; ++kb) {
        const int cur = kb & 1, nxt = cur ^ 1;
        float4 av[8];
        if (kb < 15) {
            // issue B(kb+1) -> LDS (4 GLD16) and A(kb+1) -> regs (8 float4)
            #pragma unroll
            for (int ks = 0; ks < 2; ++ks)
                #pragma unroll
                for (int i = 0; i < 2; ++i)
                    GLD16(bsrc + (size_t)((kb + 1) * 2 + ks) * 16384 + i * 4096,
                          Bs + nxt * 16384 + ks * 8192 + boff + i * 4096);
            #pragma unroll
            for (int i = 0; i < 8; ++i)
                av[i] = *(const float4*)(actx + (kb + 1) * 64 + i * 4);
        }

        #pragma unroll
        for (int ks = 0; ks < 2; ++ks) {
            bf16x8 aF[4], bF[8];
            const bf16* aP = As + cur * 16384 + ks * 8192 + fA;
            const bf16* bP = Bs + cur * 16384 + ks * 8192 + fB;
            #pragma unroll
            for (int mf = 0; mf < 4; ++mf) aF[mf] = *(const bf16x8*)(aP + mf * 512);
            #pragma unroll
            for (int nf = 0; nf < 8; ++nf) bF[nf] = *(const bf16x8*)(bP + nf * 512);
            #pragma unroll
            for (int mf = 0; mf < 4; ++mf)
                #pragma unroll
                for (int nf = 0; nf < 8; ++nf)
                    acc[mf][nf] = __builtin_amdgcn_mfma_f32_16x16x32_bf16(aF[mf], bF[nf], acc[mf][nf], 0, 0, 0);
        }

        if (kb < 15) {
            #pragma unroll
            for (int j = 0; j < 4; ++j) {
                bf16x8 a8 = { (bf16)av[2*j].x, (bf16)av[2*j].y, (bf16)av[2*j].z, (bf16)av[2*j].w,
                              (bf16)av[2*j+1].x, (bf16)av[2*j+1].y, (bf16)av[2*j+1].z, (bf16)av[2*j+1].w };
                *(bf16x8*)(As + nxt * 16384 + aoff + j * 8) = a8;
            }
        }
        __syncthreads();
    }

    // ---- epilogue: partial s(row) over this block's 256 cols ----
    float qv[8], wv[8];
    #pragma unroll
    for (int nf = 0; nf < 8; ++nf) {
        int c = h2 * 256 + wn * 128 + nf * 16 + l16;
        qv[nf] = qb[(size_t)b * H_ + c];
        wv[nf] = W2[c];
    }
    #pragma unroll
    for (int mf = 0; mf < 4; ++mf) {
        #pragma unroll
        for (int r = 0; r < 4; ++r) {
            float s = 0.0f;
            #pragma unroll
            for (int nf = 0; nf < 8; ++nf) {
                float x = acc[mf][nf][r] + qv[nf];
                float t = 1.0f - 2.0f / (1.0f + __expf(2.0f * x)); // tanh, saturates
                s = fmaf(t, wv[nf], s);
            }
            s += __shfl_xor(s, 1);
            s += __shfl_xor(s, 2);
            s += __shfl_xor(s, 4);
            s += __shfl_xor(s, 8);
            if (l16 == 0)
                red[(wm * 64 + mf * 16 + quad * 4 + r) * 2 + wn] = s;
        }
    }
    __syncthreads();
    if (tid < 256) {
        int pos = blk * 256 + tid;
        if (pos < cnt) {
            float s = red[tid * 2] + red[tid * 2 + 1];
            scorep[(size_t)h2 * (B_ * S_) + glist[(size_t)b * S_ + pos]] = s;
        }
    }
}

// ---------- Kernel S: sum halves, + b2, mask, stable softmax per batch row ----------
// masked entries read poisoned partials but are replaced by -10000 before use.
__global__ __launch_bounds__(256) void k_softmax(const float* __restrict__ scorep,
                                                 const float* __restrict__ b2,
                                                 const int*   __restrict__ mask,
                                                 float* __restrict__ p_out) {
    int b = blockIdx.x, tid = threadIdx.x;
    __shared__ float red[256];
    float loc[8];
    float b2v = b2[0];
    float mx = -1e30f;
    #pragma unroll
    for (int i = 0; i < 8; ++i) {
        size_t r = (size_t)b * S_ + i * 256 + tid;
        float v = scorep[r] + scorep[(size_t)(B_ * S_) + r] + b2v;
        if (mask[r] == 0) v = -10000.0f;
        loc[i] = v;
        mx = fmaxf(mx, v);
    }
    red[tid] = mx; __syncthreads();
    for (int o = 128; o > 0; o >>= 1) {
        if (tid < o) red[tid] = fmaxf(red[tid], red[tid + o]);
        __syncthreads();
    }
    mx = red[0]; __syncthreads();
    float se = 0.0f;
    #pragma unroll
    for (int i = 0; i < 8; ++i) {
        float e = __expf(loc[i] - mx);
        loc[i] = e;
        se += e;
    }
    red[tid] = se; __syncthreads();
    for (int o = 128; o > 0; o >>= 1) {
        if (tid < o) red[tid] += red[tid + o];
        __syncthreads();
    }
    float inv = 1.0f / red[0];
    #pragma unroll
    for (int i = 0; i < 8; ++i)
        p_out[(size_t)b * S_ + i * 256 + tid] = loc[i] * inv;
}

// ---------- Kernel E: partial expected_ctx over 128-entry compacted chunks ----------
// masked rows have p == 0 exactly (exp(-10000-mx) underflows) and are skipped.
__global__ __launch_bounds__(256) void k_expected(const float* __restrict__ ctx,
                                                  const float* __restrict__ p,
                                                  const int*   __restrict__ glist,
                                                  const int*   __restrict__ cnts,
                                                  float* __restrict__ partial) {
    int b = blockIdx.x, ch = blockIdx.y, tid = threadIdx.x;
    const int cnt = cnts[b];
    const int n0 = ch * 128;
    int nloc = cnt - n0;
    if (nloc > 128) nloc = 128;
    __shared__ float ps[128];
    __shared__ int   gi[128];
    if (tid < 128) {
        int g = glist[(size_t)b * S_ + n0 + tid];
        gi[tid] = g;
        ps[tid] = (n0 + tid < cnt) ? p[g] : 0.0f;
    }
    __syncthreads();
    float ax = 0.f, ay = 0.f, az = 0.f, aw = 0.f;
    #pragma unroll 4
    for (int s = 0; s < nloc; ++s) {
        const float4 v = *(const float4*)(ctx + (size_t)gi[s] * DC + tid * 4);
        float w = ps[s];
        ax = fmaf(w, v.x, ax);
        ay = fmaf(w, v.y, ay);
        az = fmaf(w, v.z, az);
        aw = fmaf(w, v.w, aw);
    }
    float4 o = { ax, ay, az, aw };
    *(float4*)(partial + ((size_t)(b * NCH + ch)) * DC + tid * 4) = o;
}

// ---------- Kernel R: reduce chunks -> expected_ctx ----------
__global__ __launch_bounds__(256) void k_reduce(const float* __restrict__ partial,
                                                float* __restrict__ out) {
    int b = blockIdx.x, tid = threadIdx.x;
    float4 acc = { 0.f, 0.f, 0.f, 0.f };
    #pragma unroll
    for (int c = 0; c < NCH; ++c) {
        const float4 v = *(const float4*)(partial + ((size_t)(b * NCH + c)) * DC + tid * 4);
        acc.x += v.x; acc.y += v.y; acc.z += v.z; acc.w += v.w;
    }
    *(float4*)(out + (size_t)b * DC + tid * 4) = acc;
}

extern "C" void kernel_launch(void* const* d_in, const int* in_sizes, int n_in,
                              void* d_out, int out_size, void* d_ws, size_t ws_size,
                              hipStream_t stream) {
    (void)in_sizes; (void)n_in; (void)out_size; (void)ws_size;
    const float* ctx   = (const float*)d_in[0];
    const float* query = (const float*)d_in[1];
    const float* W1    = (const float*)d_in[2];
    const float* b1    = (const float*)d_in[3];
    const float* W2    = (const float*)d_in[4];
    const float* b2    = (const float*)d_in[5];
    const int*   mask  = (const int*)d_in[6];

    float* out      = (float*)d_out;
    float* expected = out;                 // 32*1024
    float* p_out    = out + 32768;         // 32*2048

    char* w = (char*)d_ws;
    bf16*  WcT2      = (bf16*)w;                                    // 1 MB  [kb][h][kk]
    float* qb        = (float*)(w + (1 << 20));                     // 64 KB
    float* scorep    = (float*)(w + (1 << 20) + (64 << 10));        // 512 KB (two halves)
    int*   glist     = (int*)  (w + (1 << 20) + (576 << 10));       // 256 KB
    int*   cnts      = (int*)  (w + (1 << 20) + (832 << 10));       // 128 B
    float* partial_e = (float*)(w + (2 << 20));                     // 2 MB

    k_prep    <<<544, 256, 0, stream>>>(W1, query, b1, mask, WcT2, qb, glist, cnts);
    k_gemm    <<<B_ * NRB * 2, 512, 0, stream>>>(ctx, WcT2, qb, W2, glist, cnts, scorep);
    k_softmax <<<B_, 256, 0, stream>>>(scorep, b2, mask, p_out);
    k_expected<<<dim3(B_, NCH), 256, 0, stream>>>(ctx, p_out, glist, cnts, partial_e);
    k_reduce  <<<B_, 256, 0, stream>>>(partial_e, expected);
}